// Round 1
// baseline (378.246 us; speedup 1.0000x reference)
//
#include <hip/hip_runtime.h>
#include <cmath>

// Problem shape is fixed by the reference: x = (8, 3, 1024, 1024) fp32.
#define BB   8
#define HH   1024
#define WW   1024
#define HWSZ (HH * WW)

// ---- compile-time gaussian weights (matches np: exp(-d^2/(2 sigma^2)) / sum) ----
constexpr double cexp(double v) {
    // Taylor series; |v| <= 2.0 here, converges to full double precision.
    double term = 1.0, sum = 1.0;
    for (int i = 1; i < 64; ++i) { term *= v / (double)i; sum += term; }
    return sum;
}

struct GW { float g31[31]; float g7[7]; };

constexpr GW make_gw() {
    GW r{};
    double t31[31]; double s31 = 0.0;
    for (int i = 0; i < 31; ++i) { double d = (double)(i - 15); t31[i] = cexp(-d * d / 128.0); s31 += t31[i]; }
    for (int i = 0; i < 31; ++i) r.g31[i] = (float)(t31[i] / s31);
    double t7[7]; double s7 = 0.0;
    for (int i = 0; i < 7; ++i) { double d = (double)(i - 3); t7[i] = cexp(-d * d / 4.5); s7 += t7[i]; }
    for (int i = 0; i < 7; ++i) r.g7[i] = (float)(t7[i] / s7);
    return r;
}

__constant__ GW GWC = make_gw();

// ---------------------------------------------------------------------------
// Kernel 1: one block per (b, y) row. Compute luma for the row into LDS,
// then horizontal 31-tap and 7-tap blurs (zero padding at row edges).
// Writes h31, h7 (each [B, H, W] fp32) to workspace.
// Separable conv with zero padding commutes, so H-pass-first == reference.
// ---------------------------------------------------------------------------
__global__ __launch_bounds__(256)
void k1_luma_hblur(const float* __restrict__ x,
                   float* __restrict__ h31o,
                   float* __restrict__ h7o) {
    __shared__ __align__(16) float lrow[WW + 32];  // 16 zero-pad each side

    const int row = blockIdx.x;           // b*HH + y
    const int t   = threadIdx.x;          // 0..255, each owns 4 pixels
    const int b   = row >> 10;
    const int y   = row & (HH - 1);

    const size_t cbase = (size_t)b * 3 * HWSZ + (size_t)y * WW + 4 * t;
    const float4 R  = *(const float4*)(x + cbase);
    const float4 G  = *(const float4*)(x + cbase + HWSZ);
    const float4 Bc = *(const float4*)(x + cbase + 2 * HWSZ);

    float4 L;
    L.x = 0.2126f * R.x + 0.7152f * G.x + 0.0722f * Bc.x;
    L.y = 0.2126f * R.y + 0.7152f * G.y + 0.0722f * Bc.y;
    L.z = 0.2126f * R.z + 0.7152f * G.z + 0.0722f * Bc.z;
    L.w = 0.2126f * R.w + 0.7152f * G.w + 0.0722f * Bc.w;

    *(float4*)(lrow + 16 + 4 * t) = L;
    if (t < 4) {
        *(float4*)(lrow + 4 * t)           = make_float4(0.f, 0.f, 0.f, 0.f);
        *(float4*)(lrow + 16 + WW + 4 * t) = make_float4(0.f, 0.f, 0.f, 0.f);
    }
    __syncthreads();

    // Register window: pixels 4t-16 .. 4t+19  (lrow index 4t .. 4t+35)
    float w[36];
    #pragma unroll
    for (int i = 0; i < 9; ++i)
        *(float4*)(w + 4 * i) = *(const float4*)(lrow + 4 * t + 4 * i);

    float o31a[4], o7a[4];
    #pragma unroll
    for (int j = 0; j < 4; ++j) {
        // pixel p = 4t + j; taps p-15..p+15 -> w[j+1 .. j+31]
        float acc = 0.f;
        #pragma unroll
        for (int s = 0; s < 31; ++s) acc += GWC.g31[s] * w[j + 1 + s];
        o31a[j] = acc;
        // taps p-3..p+3 -> w[j+13 .. j+19]
        float acc2 = 0.f;
        #pragma unroll
        for (int s = 0; s < 7; ++s) acc2 += GWC.g7[s] * w[j + 13 + s];
        o7a[j] = acc2;
    }

    const size_t obase = (size_t)row * WW + 4 * t;
    *(float4*)(h31o + obase) = make_float4(o31a[0], o31a[1], o31a[2], o31a[3]);
    *(float4*)(h7o  + obase) = make_float4(o7a[0],  o7a[1],  o7a[2],  o7a[3]);
}

// ---------------------------------------------------------------------------
// Kernel 2: one block per (b, y) row. Vertical 31-tap blur of h31 and 7-tap
// of h7 (zero pad top/bottom), recompute luma from x, apply enhancement,
// write all 3 output channels.
// ---------------------------------------------------------------------------
__global__ __launch_bounds__(256)
void k2_vblur_combine(const float* __restrict__ x,
                      const float* __restrict__ h31i,
                      const float* __restrict__ h7i,
                      const float* __restrict__ clar,
                      const float* __restrict__ tex,
                      float* __restrict__ out) {
    const int row = blockIdx.x;
    const int t   = threadIdx.x;
    const int b   = row >> 10;
    const int y   = row & (HH - 1);

    const float* h31b = h31i + (size_t)b * HWSZ + 4 * t;
    const float* h7b  = h7i  + (size_t)b * HWSZ + 4 * t;

    float a31x = 0.f, a31y = 0.f, a31z = 0.f, a31w = 0.f;
    float a7x = 0.f, a7y = 0.f, a7z = 0.f, a7w = 0.f;

    #pragma unroll
    for (int k = 0; k < 31; ++k) {
        const int yy = y + k - 15;
        if ((unsigned)yy < (unsigned)HH) {           // wave-uniform branch
            const float g = GWC.g31[k];
            const float4 v = *(const float4*)(h31b + (size_t)yy * WW);
            a31x += g * v.x; a31y += g * v.y; a31z += g * v.z; a31w += g * v.w;
            if (k >= 12 && k < 19) {                 // compile-time after unroll
                const float g2 = GWC.g7[k - 12];
                const float4 u = *(const float4*)(h7b + (size_t)yy * WW);
                a7x += g2 * u.x; a7y += g2 * u.y; a7z += g2 * u.z; a7w += g2 * u.w;
            }
        }
    }

    const float ca = tanhf(*clar) * 0.5f;
    const float ta = tanhf(*tex) * 0.3f;

    const size_t cbase = (size_t)b * 3 * HWSZ + (size_t)y * WW + 4 * t;
    const float4 R  = *(const float4*)(x + cbase);
    const float4 G  = *(const float4*)(x + cbase + HWSZ);
    const float4 Bc = *(const float4*)(x + cbase + 2 * HWSZ);

    float ro[4], go[4], bo[4];
    const float rr[4] = {R.x, R.y, R.z, R.w};
    const float gg[4] = {G.x, G.y, G.z, G.w};
    const float bb[4] = {Bc.x, Bc.y, Bc.z, Bc.w};
    const float a31[4] = {a31x, a31y, a31z, a31w};
    const float a7[4]  = {a7x, a7y, a7z, a7w};

    #pragma unroll
    for (int j = 0; j < 4; ++j) {
        const float L     = 0.2126f * rr[j] + 0.7152f * gg[j] + 0.0722f * bb[j];
        const float le    = L + ca * (L - a31[j]) + ta * (L - a7[j]);
        const float ratio = (le + 1e-6f) / (L + 1e-6f);
        ro[j] = fminf(fmaxf(rr[j] * ratio, 0.f), 1.f);
        go[j] = fminf(fmaxf(gg[j] * ratio, 0.f), 1.f);
        bo[j] = fminf(fmaxf(bb[j] * ratio, 0.f), 1.f);
    }

    *(float4*)(out + cbase)            = make_float4(ro[0], ro[1], ro[2], ro[3]);
    *(float4*)(out + cbase + HWSZ)     = make_float4(go[0], go[1], go[2], go[3]);
    *(float4*)(out + cbase + 2 * HWSZ) = make_float4(bo[0], bo[1], bo[2], bo[3]);
}

extern "C" void kernel_launch(void* const* d_in, const int* in_sizes, int n_in,
                              void* d_out, int out_size, void* d_ws, size_t ws_size,
                              hipStream_t stream) {
    const float* x    = (const float*)d_in[0];
    const float* clar = (const float*)d_in[1];
    const float* tex  = (const float*)d_in[2];
    float* out = (float*)d_out;

    float* h31 = (float*)d_ws;                      // [B,H,W] fp32 = 32 MB
    float* h7  = h31 + (size_t)BB * HWSZ;           // [B,H,W] fp32 = 32 MB

    dim3 grid(BB * HH);   // 8192 blocks, one image row each; consecutive
    dim3 block(256);      // blocks = consecutive y -> vertical-tap L2 reuse

    hipLaunchKernelGGL(k1_luma_hblur,    grid, block, 0, stream, x, h31, h7);
    hipLaunchKernelGGL(k2_vblur_combine, grid, block, 0, stream, x, h31, h7, clar, tex, out);
}

// Round 2
// 286.906 us; speedup vs baseline: 1.3184x; 1.3184x over previous
//
#include <hip/hip_runtime.h>
#include <cmath>

// Fixed problem shape: x = (8, 3, 1024, 1024) fp32.
#define HH   1024
#define WW   1024
#define HW   (HH * WW)

#define SW   256      // strip width (output px per block)
#define TH   64       // band height (output rows per block)
#define NB   16       // bands  = HH/TH
#define NS   4        // strips = WW/SW
#define D31  35       // ring depth for 31-tap h-blur rows
#define D7   23       // ring depth for 7-tap h-blur rows
#define STW  288      // stage row width = SW + 32 (cols x0-16 .. x0+271)

// ---- compile-time gaussian weights (matches np: exp(-d^2/(2 sigma^2)) / sum) ----
constexpr double cexp(double v) {
    double term = 1.0, sum = 1.0;
    for (int i = 1; i < 64; ++i) { term *= v / (double)i; sum += term; }
    return sum;
}
struct GW { float g31[31]; float g7[7]; };
constexpr GW make_gw() {
    GW r{};
    double t31[31]; double s31 = 0.0;
    for (int i = 0; i < 31; ++i) { double d = (double)(i - 15); t31[i] = cexp(-d * d / 128.0); s31 += t31[i]; }
    for (int i = 0; i < 31; ++i) r.g31[i] = (float)(t31[i] / s31);
    double t7[7]; double s7 = 0.0;
    for (int i = 0; i < 7; ++i) { double d = (double)(i - 3); t7[i] = cexp(-d * d / 4.5); s7 += t7[i]; }
    for (int i = 0; i < 7; ++i) r.g7[i] = (float)(t7[i] / s7);
    return r;
}
__constant__ GW GWC = make_gw();

// ---------------------------------------------------------------------------
// Fused scan kernel. Block = 128 threads (2 waves).
//   wave 1 (t>=64): producer — load x, luma, horizontal 31/7-tap -> LDS rings
//   wave 0 (t<64) : consumer — vertical 31/7-tap from rings (2 rows/step,
//                   sharing 30/31 taps), combine with x, store out
// Rings hold h-blurred rows; lag between produced row and consumed row = 18,
// so consumers only read rows written before the previous step's barrier.
// Zero padding (rows/cols outside the image) matches jax conv exactly.
// ---------------------------------------------------------------------------
__global__ __launch_bounds__(128)
void fused_clarity(const float* __restrict__ x,
                   const float* __restrict__ clar,
                   const float* __restrict__ tex,
                   float* __restrict__ out) {
    __shared__ __align__(16) float ring31[D31][SW];
    __shared__ __align__(16) float ring7 [D7 ][SW];
    __shared__ __align__(16) float stage [2][STW];

    const int band  = blockIdx.x & (NB - 1);
    const int strip = (blockIdx.x / NB) & (NS - 1);
    const int b     = blockIdx.x / (NB * NS);
    const int y0 = band * TH;
    const int x0 = strip * SW;
    const int t  = threadIdx.x;
    const int pt = t & 63;
    const bool isProd = (t >= 64);

    const float ca = tanhf(clar[0]) * 0.5f;
    const float ta = tanhf(tex[0]) * 0.3f;

    const float* xb = x   + (size_t)b * 3 * HW;
    float*       ob = out + (size_t)b * 3 * HW;

    for (int i = 0; i < 49; ++i) {
        const int ylead = y0 - 16 + 2 * i;
        const bool doProd = (ylead <= y0 + TH + 14);

        // ---- producers: stage luma for rows ylead, ylead+1 ----
        if (isProd && doProd) {
            #pragma unroll
            for (int r = 0; r < 2; ++r) {
                const int y = ylead + r;
                if ((unsigned)y < (unsigned)HH) {
                    const float* xr = xb + (size_t)y * WW;
                    #pragma unroll
                    for (int cc = 0; cc < 2; ++cc) {
                        const int c = pt + 64 * cc;          // chunk id, 72 per row
                        if (c < 72) {
                            const int col = x0 - 16 + 4 * c;
                            float4 L = make_float4(0.f, 0.f, 0.f, 0.f);
                            if ((unsigned)col < (unsigned)WW) {   // float4 fully in/out
                                const float4 R  = *(const float4*)(xr + col);
                                const float4 G  = *(const float4*)(xr + HW + col);
                                const float4 Bc = *(const float4*)(xr + 2 * HW + col);
                                L.x = 0.2126f * R.x + 0.7152f * G.x + 0.0722f * Bc.x;
                                L.y = 0.2126f * R.y + 0.7152f * G.y + 0.0722f * Bc.y;
                                L.z = 0.2126f * R.z + 0.7152f * G.z + 0.0722f * Bc.z;
                                L.w = 0.2126f * R.w + 0.7152f * G.w + 0.0722f * Bc.w;
                            }
                            *(float4*)&stage[r][4 * c] = L;
                        }
                    }
                }
            }
        }
        __syncthreads();   // stage visible to all producer lanes

        if (isProd) {
            // ---- producers: horizontal blur -> rings ----
            if (doProd) {
                #pragma unroll
                for (int r = 0; r < 2; ++r) {
                    const int y   = ylead + r;
                    const int s31 = (y + 70) % D31;   // == y mod 35
                    const int s7  = (y + 46) % D7;    // == y mod 23
                    float4 o31 = make_float4(0.f, 0.f, 0.f, 0.f);
                    float4 o7  = make_float4(0.f, 0.f, 0.f, 0.f);
                    if ((unsigned)y < (unsigned)HH) {
                        float w[36];
                        #pragma unroll
                        for (int q = 0; q < 9; ++q)
                            *(float4*)(w + 4 * q) = *(const float4*)&stage[r][4 * pt + 4 * q];
                        float a0 = 0.f, a1 = 0.f, a2 = 0.f, a3 = 0.f;
                        #pragma unroll
                        for (int s = 0; s < 31; ++s) {
                            const float g = GWC.g31[s];
                            a0 += g * w[1 + s]; a1 += g * w[2 + s];
                            a2 += g * w[3 + s]; a3 += g * w[4 + s];
                        }
                        float b0 = 0.f, b1 = 0.f, b2 = 0.f, b3 = 0.f;
                        #pragma unroll
                        for (int s = 0; s < 7; ++s) {
                            const float g = GWC.g7[s];
                            b0 += g * w[13 + s]; b1 += g * w[14 + s];
                            b2 += g * w[15 + s]; b3 += g * w[16 + s];
                        }
                        o31 = make_float4(a0, a1, a2, a3);
                        o7  = make_float4(b0, b1, b2, b3);
                    }
                    *(float4*)&ring31[s31][4 * pt] = o31;   // zero rows for pad
                    *(float4*)&ring7 [s7 ][4 * pt] = o7;
                }
            }
        } else if (i >= 17) {
            // ---- consumers: vertical blur + combine for rows r0, r0+1 ----
            const int r0 = ylead - 18;                 // y0 <= r0 <= y0+TH-2
            const int cx = x0 + 4 * pt;
            const float* p0 = xb + (size_t)r0 * WW + cx;
            const float* p1 = p0 + WW;
            const float4 R0 = *(const float4*)(p0);
            const float4 G0 = *(const float4*)(p0 + HW);
            const float4 B0 = *(const float4*)(p0 + 2 * HW);
            const float4 R1 = *(const float4*)(p1);
            const float4 G1 = *(const float4*)(p1 + HW);
            const float4 B1 = *(const float4*)(p1 + 2 * HW);

            float4 A0 = make_float4(0.f, 0.f, 0.f, 0.f);   // 31-tap, row r0
            float4 A1 = make_float4(0.f, 0.f, 0.f, 0.f);   // 31-tap, row r0+1
            int s = (r0 - 15 + 70) % D31;
            #pragma unroll
            for (int k = 0; k < 32; ++k) {                 // 32 rows shared by both
                const float4 v = *(const float4*)&ring31[s][4 * pt];
                if (k < 31) {
                    const float g = GWC.g31[k];
                    A0.x += g * v.x; A0.y += g * v.y; A0.z += g * v.z; A0.w += g * v.w;
                }
                if (k > 0) {
                    const float g = GWC.g31[k - 1];
                    A1.x += g * v.x; A1.y += g * v.y; A1.z += g * v.z; A1.w += g * v.w;
                }
                ++s; if (s >= D31) s = 0;
            }
            float4 C0 = make_float4(0.f, 0.f, 0.f, 0.f);   // 7-tap, row r0
            float4 C1 = make_float4(0.f, 0.f, 0.f, 0.f);   // 7-tap, row r0+1
            int s7 = (r0 - 3 + 46) % D7;
            #pragma unroll
            for (int k = 0; k < 8; ++k) {
                const float4 u = *(const float4*)&ring7[s7][4 * pt];
                if (k < 7) {
                    const float g = GWC.g7[k];
                    C0.x += g * u.x; C0.y += g * u.y; C0.z += g * u.z; C0.w += g * u.w;
                }
                if (k > 0) {
                    const float g = GWC.g7[k - 1];
                    C1.x += g * u.x; C1.y += g * u.y; C1.z += g * u.z; C1.w += g * u.w;
                }
                ++s7; if (s7 >= D7) s7 = 0;
            }

            const float rr0[4] = {R0.x, R0.y, R0.z, R0.w};
            const float gg0[4] = {G0.x, G0.y, G0.z, G0.w};
            const float bb0[4] = {B0.x, B0.y, B0.z, B0.w};
            const float rr1[4] = {R1.x, R1.y, R1.z, R1.w};
            const float gg1[4] = {G1.x, G1.y, G1.z, G1.w};
            const float bb1[4] = {B1.x, B1.y, B1.z, B1.w};
            const float aa0[4] = {A0.x, A0.y, A0.z, A0.w};
            const float aa1[4] = {A1.x, A1.y, A1.z, A1.w};
            const float cc0[4] = {C0.x, C0.y, C0.z, C0.w};
            const float cc1[4] = {C1.x, C1.y, C1.z, C1.w};

            float ro0[4], go0[4], bo0[4], ro1[4], go1[4], bo1[4];
            #pragma unroll
            for (int j = 0; j < 4; ++j) {
                {
                    const float L     = 0.2126f * rr0[j] + 0.7152f * gg0[j] + 0.0722f * bb0[j];
                    const float le    = L + ca * (L - aa0[j]) + ta * (L - cc0[j]);
                    const float ratio = (le + 1e-6f) / (L + 1e-6f);
                    ro0[j] = fminf(fmaxf(rr0[j] * ratio, 0.f), 1.f);
                    go0[j] = fminf(fmaxf(gg0[j] * ratio, 0.f), 1.f);
                    bo0[j] = fminf(fmaxf(bb0[j] * ratio, 0.f), 1.f);
                }
                {
                    const float L     = 0.2126f * rr1[j] + 0.7152f * gg1[j] + 0.0722f * bb1[j];
                    const float le    = L + ca * (L - aa1[j]) + ta * (L - cc1[j]);
                    const float ratio = (le + 1e-6f) / (L + 1e-6f);
                    ro1[j] = fminf(fmaxf(rr1[j] * ratio, 0.f), 1.f);
                    go1[j] = fminf(fmaxf(gg1[j] * ratio, 0.f), 1.f);
                    bo1[j] = fminf(fmaxf(bb1[j] * ratio, 0.f), 1.f);
                }
            }

            float* q0 = ob + (size_t)r0 * WW + cx;
            float* q1 = q0 + WW;
            *(float4*)(q0)          = make_float4(ro0[0], ro0[1], ro0[2], ro0[3]);
            *(float4*)(q0 + HW)     = make_float4(go0[0], go0[1], go0[2], go0[3]);
            *(float4*)(q0 + 2 * HW) = make_float4(bo0[0], bo0[1], bo0[2], bo0[3]);
            *(float4*)(q1)          = make_float4(ro1[0], ro1[1], ro1[2], ro1[3]);
            *(float4*)(q1 + HW)     = make_float4(go1[0], go1[1], go1[2], go1[3]);
            *(float4*)(q1 + 2 * HW) = make_float4(bo1[0], bo1[1], bo1[2], bo1[3]);
        }
        __syncthreads();   // ring rows written this step become readable next step
    }
}

extern "C" void kernel_launch(void* const* d_in, const int* in_sizes, int n_in,
                              void* d_out, int out_size, void* d_ws, size_t ws_size,
                              hipStream_t stream) {
    const float* x    = (const float*)d_in[0];
    const float* clar = (const float*)d_in[1];
    const float* tex  = (const float*)d_in[2];
    float* out = (float*)d_out;

    dim3 grid(8 * NS * NB);   // 512 blocks: 8 images x 4 strips x 16 bands
    dim3 block(128);          // 2 waves: producer + consumer
    hipLaunchKernelGGL(fused_clarity, grid, block, 0, stream, x, clar, tex, out);
}

// Round 3
// 226.263 us; speedup vs baseline: 1.6717x; 1.2680x over previous
//
#include <hip/hip_runtime.h>
#include <hip/hip_fp16.h>
#include <cmath>

// Fixed problem shape: x = (8, 3, 1024, 1024) fp32.
#define HH   1024
#define WW   1024
#define HW   (HH * WW)

#define SW   128      // tile width  (output cols per block)
#define TH   64       // tile height (output rows per block)
#define T31R 94       // h31 tile rows = TH + 30
#define T7R  70       // h7  tile rows = TH + 6
#define STW  160      // luma stage row width = SW + 32

// ---- compile-time gaussian weights (matches np: exp(-d^2/(2 sigma^2)) / sum) ----
constexpr double cexp(double v) {
    double term = 1.0, sum = 1.0;
    for (int i = 1; i < 64; ++i) { term *= v / (double)i; sum += term; }
    return sum;
}
struct GW { float g31[31]; float g7[7]; };
constexpr GW make_gw() {
    GW r{};
    double t31[31]; double s31 = 0.0;
    for (int i = 0; i < 31; ++i) { double d = (double)(i - 15); t31[i] = cexp(-d * d / 128.0); s31 += t31[i]; }
    for (int i = 0; i < 31; ++i) r.g31[i] = (float)(t31[i] / s31);
    double t7[7]; double s7 = 0.0;
    for (int i = 0; i < 7; ++i) { double d = (double)(i - 3); t7[i] = cexp(-d * d / 4.5); s7 += t7[i]; }
    for (int i = 0; i < 7; ++i) r.g7[i] = (float)(t7[i] / s7);
    return r;
}
__constant__ GW GWC = make_gw();

// ---------------------------------------------------------------------------
// Tile kernel: block = 256 threads, output tile 64 rows x 128 cols.
// Phase 1 (12 iters): stage 8 luma rows (+/-16 col halo) cooperatively,
//   each wave h-blurs 2 rows (31-tap & 7-tap) -> fp16 LDS tiles.
// Phase 2: vertical conv from LDS (register sliding window), recompute luma
//   from x (L2/L3-hot re-read), combine, store.
// Zero padding outside the image matches jax conv exactly (pad rows/cols
// contribute 0 to both passes).
// LDS: 94*128*2 + 70*128*2 + 8*160*4 = 47 KB -> 3 blocks/CU, 12 waves/CU.
// ---------------------------------------------------------------------------
__global__ __launch_bounds__(256, 3)
void fused_tile(const float* __restrict__ x,
                const float* __restrict__ clar,
                const float* __restrict__ tex,
                float* __restrict__ out) {
    __shared__ __align__(16) __half t31s[T31R][SW];
    __shared__ __align__(16) __half t7s [T7R][SW];
    __shared__ __align__(16) float stage[8][STW];

    // XCD swizzle: all 16 bands of one (img,strip) column land on one XCD
    // (dispatch round-robins blockIdx % 8 across XCDs), so the 30-row halo
    // overlap between adjacent bands reuses that XCD's L2.
    const int id    = blockIdx.x;
    const int xcd   = id & 7;
    const int k     = id >> 3;
    const int combo = xcd * 8 + (k & 7);   // 0..63 = img*8 + strip
    const int band  = k >> 3;              // 0..15
    const int img   = combo >> 3;
    const int strip = combo & 7;

    const int y0 = band * TH;
    const int x0 = strip * SW;
    const int t  = threadIdx.x;
    const int w  = t >> 6;
    const int l  = t & 63;

    const float* xb = x   + (size_t)img * 3 * HW;
    float*       ob = out + (size_t)img * 3 * HW;

    // ---------------- phase 1: horizontal blurs into LDS tiles ----------------
    for (int it = 0; it < 12; ++it) {
        const int gbase = it * 8;   // tile rows gbase .. gbase+7 this iter

        // cooperative luma staging: 8 rows x 40 float4-chunks = 320 chunks
        #pragma unroll
        for (int cb = 0; cb < 2; ++cb) {
            const int c = t + 256 * cb;
            if (c < 320) {
                const int r  = c / 40;
                const int cc = c - 40 * r;
                const int tr = gbase + r;
                const int y  = y0 - 15 + tr;
                const int col = x0 - 16 + 4 * cc;
                float4 L = make_float4(0.f, 0.f, 0.f, 0.f);
                if (tr < T31R && (unsigned)y < (unsigned)HH && (unsigned)col < (unsigned)WW) {
                    const float* xr = xb + (size_t)y * WW + col;
                    const float4 R  = *(const float4*)(xr);
                    const float4 G  = *(const float4*)(xr + HW);
                    const float4 Bc = *(const float4*)(xr + 2 * HW);
                    L.x = fmaf(0.2126f, R.x, fmaf(0.7152f, G.x, 0.0722f * Bc.x));
                    L.y = fmaf(0.2126f, R.y, fmaf(0.7152f, G.y, 0.0722f * Bc.y));
                    L.z = fmaf(0.2126f, R.z, fmaf(0.7152f, G.z, 0.0722f * Bc.z));
                    L.w = fmaf(0.2126f, R.w, fmaf(0.7152f, G.w, 0.0722f * Bc.w));
                }
                if (r < 8) *(float4*)&stage[r][4 * cc] = L;
            }
        }
        __syncthreads();

        // each wave h-blurs stage rows 2w, 2w+1; lane: row = l>>5, 4 cols each
        {
            const int lr = 2 * w + (l >> 5);
            const int tr = gbase + lr;
            const int c4 = (l & 31) * 4;
            if (tr < T31R) {
                float win[36];
                #pragma unroll
                for (int q = 0; q < 9; ++q)
                    *(float4*)&win[4 * q] = *(const float4*)&stage[lr][c4 + 4 * q];
                float o[4] = {0.f, 0.f, 0.f, 0.f};
                float p[4] = {0.f, 0.f, 0.f, 0.f};
                #pragma unroll
                for (int s = 0; s < 31; ++s) {
                    const float g = GWC.g31[s];
                    o[0] = fmaf(g, win[1 + s], o[0]);
                    o[1] = fmaf(g, win[2 + s], o[1]);
                    o[2] = fmaf(g, win[3 + s], o[2]);
                    o[3] = fmaf(g, win[4 + s], o[3]);
                }
                #pragma unroll
                for (int s = 0; s < 7; ++s) {
                    const float g = GWC.g7[s];
                    p[0] = fmaf(g, win[13 + s], p[0]);
                    p[1] = fmaf(g, win[14 + s], p[1]);
                    p[2] = fmaf(g, win[15 + s], p[2]);
                    p[3] = fmaf(g, win[16 + s], p[3]);
                }
                *(__half2*)&t31s[tr][c4]     = __floats2half2_rn(o[0], o[1]);
                *(__half2*)&t31s[tr][c4 + 2] = __floats2half2_rn(o[2], o[3]);
                if (tr >= 12 && tr < 12 + T7R) {
                    *(__half2*)&t7s[tr - 12][c4]     = __floats2half2_rn(p[0], p[1]);
                    *(__half2*)&t7s[tr - 12][c4 + 2] = __floats2half2_rn(p[2], p[3]);
                }
            }
        }
        __syncthreads();
    }

    // ---------------- phase 2: vertical blurs + combine ----------------
    const float ca = tanhf(clar[0]) * 0.5f;
    const float ta = tanhf(tex[0]) * 0.3f;

    const int cp = t & 63;        // half2 column pair: cols 2cp, 2cp+1
    const int rg = t >> 6;        // row group 0..3
    const int r0 = rg * 16;       // output rows r0..r0+15 (tile-relative)

    // output row r: h31 taps = tile rows r..r+30; h7 taps = t7 rows r..r+6
    float2 w31[31];
    #pragma unroll
    for (int q = 0; q < 30; ++q)
        w31[q] = __half22float2(*(const __half2*)&t31s[r0 + q][2 * cp]);
    float2 w7[7];
    #pragma unroll
    for (int q = 0; q < 6; ++q)
        w7[q] = __half22float2(*(const __half2*)&t7s[r0 + q][2 * cp]);

    #pragma unroll
    for (int j = 0; j < 16; ++j) {
        w31[(30 + j) % 31] = __half22float2(*(const __half2*)&t31s[r0 + 30 + j][2 * cp]);
        w7 [(6 + j) % 7]   = __half22float2(*(const __half2*)&t7s [r0 + 6 + j][2 * cp]);

        float ax = 0.f, ay = 0.f;
        #pragma unroll
        for (int q = 0; q < 31; ++q) {
            const float g = GWC.g31[q];
            const float2 v = w31[(j + q) % 31];
            ax = fmaf(g, v.x, ax);
            ay = fmaf(g, v.y, ay);
        }
        float cx = 0.f, cy = 0.f;
        #pragma unroll
        for (int q = 0; q < 7; ++q) {
            const float g = GWC.g7[q];
            const float2 v = w7[(j + q) % 7];
            cx = fmaf(g, v.x, cx);
            cy = fmaf(g, v.y, cy);
        }

        const int y = y0 + r0 + j;
        const float* px = xb + (size_t)y * WW + x0 + 2 * cp;
        const float2 R  = *(const float2*)(px);
        const float2 G  = *(const float2*)(px + HW);
        const float2 Bc = *(const float2*)(px + 2 * HW);

        const float Lx  = fmaf(0.2126f, R.x, fmaf(0.7152f, G.x, 0.0722f * Bc.x));
        const float Ly  = fmaf(0.2126f, R.y, fmaf(0.7152f, G.y, 0.0722f * Bc.y));
        const float lex = Lx + ca * (Lx - ax) + ta * (Lx - cx);
        const float ley = Ly + ca * (Ly - ay) + ta * (Ly - cy);
        const float rx  = (lex + 1e-6f) / (Lx + 1e-6f);
        const float ry  = (ley + 1e-6f) / (Ly + 1e-6f);

        float2 Ro, Go, Bo;
        Ro.x = fminf(fmaxf(R.x  * rx, 0.f), 1.f);
        Ro.y = fminf(fmaxf(R.y  * ry, 0.f), 1.f);
        Go.x = fminf(fmaxf(G.x  * rx, 0.f), 1.f);
        Go.y = fminf(fmaxf(G.y  * ry, 0.f), 1.f);
        Bo.x = fminf(fmaxf(Bc.x * rx, 0.f), 1.f);
        Bo.y = fminf(fmaxf(Bc.y * ry, 0.f), 1.f);

        float* qo = ob + (size_t)y * WW + x0 + 2 * cp;
        *(float2*)(qo)          = Ro;
        *(float2*)(qo + HW)     = Go;
        *(float2*)(qo + 2 * HW) = Bo;
    }
}

extern "C" void kernel_launch(void* const* d_in, const int* in_sizes, int n_in,
                              void* d_out, int out_size, void* d_ws, size_t ws_size,
                              hipStream_t stream) {
    const float* x    = (const float*)d_in[0];
    const float* clar = (const float*)d_in[1];
    const float* tex  = (const float*)d_in[2];
    float* out = (float*)d_out;

    dim3 grid(8 * 8 * 16);   // 1024 blocks: 8 imgs x 8 strips x 16 bands
    dim3 block(256);
    hipLaunchKernelGGL(fused_tile, grid, block, 0, stream, x, clar, tex, out);
}

// Round 4
// 198.888 us; speedup vs baseline: 1.9018x; 1.1376x over previous
//
#include <hip/hip_runtime.h>
#include <hip/hip_fp16.h>
#include <cmath>

// Fixed problem shape: x = (8, 3, 1024, 1024) fp32.
#define HH   1024
#define WW   1024
#define HW   (HH * WW)

#define SW    64      // tile width  (output cols per block)
#define TH    128     // tile height (output rows per block)
#define T31R  158     // TH + 30
#define T7R   134     // TH + 6
#define SROWS 16      // luma stage rows per iteration
#define SPIT  96      // stage row width in halves = SW + 32

// ---- compile-time gaussian weights (matches np: exp(-d^2/(2 sigma^2)) / sum) ----
constexpr double cexp(double v) {
    double term = 1.0, sum = 1.0;
    for (int i = 1; i < 64; ++i) { term *= v / (double)i; sum += term; }
    return sum;
}
struct GW { float g31[31]; float g7[7]; };
constexpr GW make_gw() {
    GW r{};
    double t31[31]; double s31 = 0.0;
    for (int i = 0; i < 31; ++i) { double d = (double)(i - 15); t31[i] = cexp(-d * d / 128.0); s31 += t31[i]; }
    for (int i = 0; i < 31; ++i) r.g31[i] = (float)(t31[i] / s31);
    double t7[7]; double s7 = 0.0;
    for (int i = 0; i < 7; ++i) { double d = (double)(i - 3); t7[i] = cexp(-d * d / 4.5); s7 += t7[i]; }
    for (int i = 0; i < 7; ++i) r.g7[i] = (float)(t7[i] / s7);
    return r;
}
__constant__ GW GWC = make_gw();

// ---------------------------------------------------------------------------
// Tile kernel: block = 256 threads, output tile 128 rows x 64 cols.
// LDS = 20224 (t31 fp16) + 17152 (t7 fp16) + 3072 (fp16 luma stage)
//     = 40448 B  ->  4 blocks/CU (163840/40448), grid 1024 = exactly 4/CU,
//     zero tail. VGPR target <=128 for 16 waves/CU.
// Phase 1 (10 iters): stage 16 luma rows (+/-16 col halo, fp16), each thread
//   h-blurs 4 px of one row (31-tap & 7-tap) -> fp16 LDS tiles.
// Phase 2: vertical conv from LDS, scalar column per thread (2 row-group
//   tasks), combine with L2-hot x re-read, store.
// Zero padding outside the image matches jax conv exactly.
// ---------------------------------------------------------------------------
__global__ __launch_bounds__(256, 4)
void fused_tile(const float* __restrict__ x,
                const float* __restrict__ clar,
                const float* __restrict__ tex,
                float* __restrict__ out) {
    __shared__ __align__(16) __half t31s [T31R][SW];
    __shared__ __align__(16) __half t7s  [T7R][SW];
    __shared__ __align__(16) __half stage[SROWS][SPIT];

    // XCD swizzle: all 8 bands of one (img,strip) column on one XCD so the
    // 30-row luma halo overlap between vertical neighbors reuses its L2.
    const int id    = blockIdx.x;
    const int xcd   = id & 7;
    const int k     = id >> 3;             // 0..127
    const int combo = xcd * 16 + (k & 15); // 0..127 = img*16 + strip
    const int band  = k >> 4;              // 0..7
    const int img   = combo >> 4;
    const int strip = combo & 15;

    const int y0 = band * TH;
    const int x0 = strip * SW;
    const int t  = threadIdx.x;

    const float* xb = x   + (size_t)img * 3 * HW;
    float*       ob = out + (size_t)img * 3 * HW;

    // ---------------- phase 1: horizontal blurs into LDS tiles ----------------
    for (int it = 0; it < 10; ++it) {
        const int gbase = it * SROWS;

        // stage 16 luma rows: 16 rows x 24 four-px units = 384 units
        #pragma unroll
        for (int s = 0; s < 2; ++s) {
            const int u = t + 256 * s;
            if (u < 384) {
                const int r   = u / 24;
                const int c8  = u - 24 * r;       // four-px unit within row
                const int tr  = gbase + r;
                const int y   = y0 - 15 + tr;
                const int col = x0 - 16 + 4 * c8; // 4-aligned: float4 fully in/out
                float4 L = make_float4(0.f, 0.f, 0.f, 0.f);
                if (tr < T31R && (unsigned)y < (unsigned)HH && (unsigned)col < (unsigned)WW) {
                    const float* xr = xb + (size_t)y * WW + col;
                    const float4 R  = *(const float4*)(xr);
                    const float4 G  = *(const float4*)(xr + HW);
                    const float4 Bc = *(const float4*)(xr + 2 * HW);
                    L.x = fmaf(0.2126f, R.x, fmaf(0.7152f, G.x, 0.0722f * Bc.x));
                    L.y = fmaf(0.2126f, R.y, fmaf(0.7152f, G.y, 0.0722f * Bc.y));
                    L.z = fmaf(0.2126f, R.z, fmaf(0.7152f, G.z, 0.0722f * Bc.z));
                    L.w = fmaf(0.2126f, R.w, fmaf(0.7152f, G.w, 0.0722f * Bc.w));
                }
                union { float2 f; __half2 h[2]; } W;
                W.h[0] = __floats2half2_rn(L.x, L.y);
                W.h[1] = __floats2half2_rn(L.z, L.w);
                *(float2*)&stage[r][4 * c8] = W.f;   // 8-byte aligned
            }
        }
        __syncthreads();

        // h-blur: thread -> row (t>>4), 4 px at cols 4*(t&15)
        {
            const int lr = t >> 4;
            const int c  = t & 15;
            const int tr = gbase + lr;
            if (tr < T31R) {
                float win[36];
                #pragma unroll
                for (int q = 0; q < 9; ++q) {
                    union { float2 f; __half2 h[2]; } U;
                    U.f = *(const float2*)&stage[lr][4 * c + 4 * q];  // 8B aligned
                    const float2 a = __half22float2(U.h[0]);
                    const float2 b = __half22float2(U.h[1]);
                    win[4 * q]     = a.x; win[4 * q + 1] = a.y;
                    win[4 * q + 2] = b.x; win[4 * q + 3] = b.y;
                }
                float o[4] = {0.f, 0.f, 0.f, 0.f};
                float p[4] = {0.f, 0.f, 0.f, 0.f};
                #pragma unroll
                for (int s = 0; s < 31; ++s) {
                    const float g = GWC.g31[s];
                    o[0] = fmaf(g, win[1 + s], o[0]);
                    o[1] = fmaf(g, win[2 + s], o[1]);
                    o[2] = fmaf(g, win[3 + s], o[2]);
                    o[3] = fmaf(g, win[4 + s], o[3]);
                }
                #pragma unroll
                for (int s = 0; s < 7; ++s) {
                    const float g = GWC.g7[s];
                    p[0] = fmaf(g, win[13 + s], p[0]);
                    p[1] = fmaf(g, win[14 + s], p[1]);
                    p[2] = fmaf(g, win[15 + s], p[2]);
                    p[3] = fmaf(g, win[16 + s], p[3]);
                }
                union { float2 f; __half2 h[2]; } W;
                W.h[0] = __floats2half2_rn(o[0], o[1]);
                W.h[1] = __floats2half2_rn(o[2], o[3]);
                *(float2*)&t31s[tr][4 * c] = W.f;
                if (tr >= 12 && tr < 12 + T7R) {
                    union { float2 f; __half2 h[2]; } V;
                    V.h[0] = __floats2half2_rn(p[0], p[1]);
                    V.h[1] = __floats2half2_rn(p[2], p[3]);
                    *(float2*)&t7s[tr - 12][4 * c] = V.f;
                }
            }
        }
        __syncthreads();
    }

    // ---------------- phase 2: vertical blurs + combine ----------------
    const float ca = tanhf(clar[0]) * 0.5f;
    const float ta = tanhf(tex[0]) * 0.3f;

    const int c = t & 63;                 // column within tile
    #pragma unroll
    for (int s = 0; s < 2; ++s) {
        const int rg = (t >> 6) + 4 * s;  // row group 0..7
        const int r0 = rg * 16;           // output rows r0..r0+15 (tile-rel)

        float w31[31];
        #pragma unroll
        for (int q = 0; q < 30; ++q) w31[q] = __half2float(t31s[r0 + q][c]);
        float w7[7];
        #pragma unroll
        for (int q = 0; q < 6; ++q) w7[q] = __half2float(t7s[r0 + q][c]);

        #pragma unroll
        for (int j = 0; j < 16; ++j) {
            w31[(30 + j) % 31] = __half2float(t31s[r0 + 30 + j][c]);
            w7 [(6 + j) % 7]   = __half2float(t7s [r0 + 6 + j][c]);

            float a31 = 0.f;
            #pragma unroll
            for (int q = 0; q < 31; ++q)
                a31 = fmaf(GWC.g31[q], w31[(j + q) % 31], a31);
            float a7 = 0.f;
            #pragma unroll
            for (int q = 0; q < 7; ++q)
                a7 = fmaf(GWC.g7[q], w7[(j + q) % 7], a7);

            const int y = y0 + r0 + j;
            const float* px = xb + (size_t)y * WW + x0 + c;
            const float R  = px[0];
            const float G  = px[HW];
            const float Bc = px[2 * HW];

            const float L     = fmaf(0.2126f, R, fmaf(0.7152f, G, 0.0722f * Bc));
            const float le    = L + ca * (L - a31) + ta * (L - a7);
            const float ratio = (le + 1e-6f) / (L + 1e-6f);

            float* qo = ob + (size_t)y * WW + x0 + c;
            qo[0]      = fminf(fmaxf(R  * ratio, 0.f), 1.f);
            qo[HW]     = fminf(fmaxf(G  * ratio, 0.f), 1.f);
            qo[2 * HW] = fminf(fmaxf(Bc * ratio, 0.f), 1.f);
        }
    }
}

extern "C" void kernel_launch(void* const* d_in, const int* in_sizes, int n_in,
                              void* d_out, int out_size, void* d_ws, size_t ws_size,
                              hipStream_t stream) {
    const float* x    = (const float*)d_in[0];
    const float* clar = (const float*)d_in[1];
    const float* tex  = (const float*)d_in[2];
    float* out = (float*)d_out;

    dim3 grid(8 * 16 * 8);   // 1024 blocks: 8 imgs x 16 strips x 8 bands = 4/CU exact
    dim3 block(256);
    hipLaunchKernelGGL(fused_tile, grid, block, 0, stream, x, clar, tex, out);
}